// Round 11
// baseline (181.519 us; speedup 1.0000x reference)
//
#include <hip/hip_runtime.h>
#include <hip/hip_bf16.h>
#include <math.h>

// B=16, D=128, OUT=128, M runtime (100000).
// v12 = v9 (best 137.6us) + spill-proof full prefetch + merged tail:
//   1. np-phase row loads: 16 NAMED float4s, CLAMPED unconditional addresses
//      (v11 lesson: conditional zero-fill loads -> allocator spilled them at
//      VGPR 84 despite cap 170; +13MB scratch WRITE). Clamped rows read row
//      M-1 (finite), weighted by p=0 in pool; score writes stay mv-guarded.
//   2. kFin merged into kC1 via v5/v6-verified atomic finisher: partials
//      atomicAdd'ed into acc2[2048] (16 writers/addr), threadfence+counter,
//      last block divides -> out. Saves a launch; kA block 72 zeroes acc2.
// Carried: 128-row tile, fused staging (reg->cvt->MFMA + ds_write), relu-split
//   scores (4-chain), plain bf16 pacc stores, 256-block kC1 geometry.

typedef __attribute__((ext_vector_type(8))) short bf16x8;
typedef __attribute__((ext_vector_type(4))) float f32x4;

__device__ __forceinline__ short f2bs(float f) {
    __hip_bfloat16 h = __float2bfloat16(f);
    return *reinterpret_cast<short*>(&h);
}
__device__ __forceinline__ float bs2f(ushort u) {
    union { unsigned int i; float f; } v; v.i = ((unsigned)u) << 16; return v.f;
}
__device__ __forceinline__ bf16x8 pack8(float4 a, float4 b) {
    bf16x8 r;
    r[0] = f2bs(a.x); r[1] = f2bs(a.y); r[2] = f2bs(a.z); r[3] = f2bs(a.w);
    r[4] = f2bs(b.x); r[5] = f2bs(b.y); r[6] = f2bs(b.z); r[7] = f2bs(b.w);
    return r;
}

__global__ __launch_bounds__(256) void kA(const float* __restrict__ W1,
                                          const float* __restrict__ xx,
                                          ushort* __restrict__ w1b,
                                          float* __restrict__ A,
                                          float* __restrict__ acc2,
                                          float* __restrict__ lsum2,
                                          int* __restrict__ counter) {
    const int bi = blockIdx.x, t = threadIdx.x;
    if (bi < 64) {
        int idx = bi * 256 + t;              // 16384 = 128o * 128d
        int o = idx >> 7, d = idx & 127;
        w1b[idx] = (ushort)f2bs(W1[o * 256 + 128 + d]);
        return;
    }
    if (bi == 72) {                          // zero final accumulators + counter
        for (int i = t; i < 2048; i += 256) acc2[i] = 0.f;
        if (t < 16) lsum2[t] = 0.f;
        if (t == 0) *counter = 0;
        return;
    }
    __shared__ float xxs[16 * 132];
    __shared__ float w1s[16 * 132];
    const int og0 = (bi - 64) * 16;
#pragma unroll
    for (int i = 0; i < 2; ++i) {
        int idx = t + 256 * i;               // 512 float4 = 16 rows * 32
        int r = idx >> 5, c4 = (idx & 31) << 2;
        *(float4*)&xxs[r * 132 + c4] = *(const float4*)&xx[r * 128 + c4];
        *(float4*)&w1s[r * 132 + c4] = *(const float4*)&W1[(og0 + r) * 256 + c4];
    }
    __syncthreads();
    const int ol = t >> 4, b = t & 15;
    float acc = 0.f;
#pragma unroll
    for (int d4 = 0; d4 < 32; ++d4) {
        float4 xv = *(float4*)&xxs[b * 132 + d4 * 4];
        float4 wv = *(float4*)&w1s[ol * 132 + d4 * 4];
        acc += xv.x * wv.x + xv.y * wv.y + xv.z * wv.z + xv.w * wv.w;
    }
    A[b * 128 + og0 + ol] = acc;
}

__global__ __launch_bounds__(256, 3) void kB(
    const float* __restrict__ in, const ushort* __restrict__ w1b,
    const float* __restrict__ W2, const float* __restrict__ A,
    float* __restrict__ lsum_g, ushort* __restrict__ pacc, int M) {
    __shared__ ushort ins[128 * 136];  // bf16 in-tile [m][d]
    __shared__ float As[16 * 128];     // A[b][o]
    __shared__ ushort pb[16 * 136];    // p bf16 [b][m(128)+pad]

    const int tid = threadIdx.x, bid = blockIdx.x;
    const int m0 = bid * 128;
    const int w = tid >> 6, lane = tid & 63;
    const int c = lane & 15, q = lane >> 4;
    const int lim = (M - m0 < 128) ? (M - m0) : 128;

    // ---- rows (clamped: no conditionals -> clean liveness, no spill) ----
    const int r0 = w * 32 + c;            // local row, mt=0
    const int r1 = r0 + 16;               // local row, mt=1
    const bool v0 = r0 < lim, v1 = r1 < lim;
    int cr0 = m0 + r0; if (cr0 > M - 1) cr0 = M - 1;
    int cr1 = m0 + r1; if (cr1 > M - 1) cr1 = M - 1;
    const float* __restrict__ row0 = in + (size_t)cr0 * 128;
    const float* __restrict__ row1 = in + (size_t)cr1 * 128;

    // ---- PREFETCH: 16 named float4, unconditional, issued before any LDS ----
    const int kq = q * 8;
    float4 pA0 = *(const float4*)&row0[kq];       float4 pA1 = *(const float4*)&row0[kq + 4];
    float4 pB0 = *(const float4*)&row0[kq + 32];  float4 pB1 = *(const float4*)&row0[kq + 36];
    float4 pC0 = *(const float4*)&row0[kq + 64];  float4 pC1 = *(const float4*)&row0[kq + 68];
    float4 pD0 = *(const float4*)&row0[kq + 96];  float4 pD1 = *(const float4*)&row0[kq + 100];
    float4 qA0 = *(const float4*)&row1[kq];       float4 qA1 = *(const float4*)&row1[kq + 4];
    float4 qB0 = *(const float4*)&row1[kq + 32];  float4 qB1 = *(const float4*)&row1[kq + 36];
    float4 qC0 = *(const float4*)&row1[kq + 64];  float4 qC1 = *(const float4*)&row1[kq + 68];
    float4 qD0 = *(const float4*)&row1[kq + 96];  float4 qD1 = *(const float4*)&row1[kq + 100];

    // ---- As stage (2048 floats, 2 float4/thread) overlaps load flight ----
#pragma unroll
    for (int i = 0; i < 2; ++i) {
        int idx = tid + 256 * i;
        *(float4*)&As[idx * 4] = *(const float4*)&A[idx * 4];
    }

    // ---- np^T via MFMA: pack prefetched rows -> {MFMA operand + ds_write} ----
    f32x4 acc[2][8];
#pragma unroll
    for (int mt = 0; mt < 2; ++mt)
#pragma unroll
        for (int ot = 0; ot < 8; ++ot) acc[mt][ot] = (f32x4){0.f, 0.f, 0.f, 0.f};

#define NP_STEP(kb, Pa, Pb, Qa, Qb)                                               \
    {                                                                             \
        const int k0 = (kb) * 32 + kq;                                            \
        bf16x8 bv0 = pack8(Pa, Pb);                                               \
        bf16x8 bv1 = pack8(Qa, Qb);                                               \
        *(bf16x8*)&ins[r0 * 136 + k0] = bv0;                                      \
        *(bf16x8*)&ins[r1 * 136 + k0] = bv1;                                      \
        _Pragma("unroll")                                                         \
        for (int ot = 0; ot < 8; ++ot) {                                          \
            bf16x8 av = *(const bf16x8*)(w1b + (ot * 16 + c) * 128 + k0);         \
            acc[0][ot] = __builtin_amdgcn_mfma_f32_16x16x32_bf16(av, bv0, acc[0][ot], 0, 0, 0); \
            acc[1][ot] = __builtin_amdgcn_mfma_f32_16x16x32_bf16(av, bv1, acc[1][ot], 0, 0, 0); \
        }                                                                         \
    }
    NP_STEP(0, pA0, pA1, qA0, qA1)
    NP_STEP(1, pB0, pB1, qB0, qB1)
    NP_STEP(2, pC0, pC1, qC0, qC1)
    NP_STEP(3, pD0, pD1, qD0, qD1)
#undef NP_STEP
    // acc[mt][ot][r] = np[m = w*32 + mt*16 + c][o = ot*16 + q*4 + r]

    // ---- per-lane w2 quads, pre-scaled by 0.5 (hoisted above barrier) ----
    f32x4 w2q[8];
#pragma unroll
    for (int ot = 0; ot < 8; ++ot) {
        f32x4 wv = *(const f32x4*)&W2[ot * 16 + q * 4];
        w2q[ot] = wv * 0.5f;
    }
    __syncthreads();   // ins + As complete

    // ---- sm = 0.5*Sum_o np*w2 per m-tile (b-invariant, hoisted) ----
    float sm0 = 0.f, sm1 = 0.f;
#pragma unroll
    for (int ot = 0; ot < 8; ++ot)
#pragma unroll
        for (int r = 0; r < 4; ++r) {
            sm0 += acc[0][ot][r] * w2q[ot][r];
            sm1 += acc[1][ot][r] * w2q[ot][r];
        }

    // ---- scores: s(b,m) = sm + 0.5*Sum_o |np+A|*w2 (per-b const dropped) ----
    // 4 independent chains (even/odd ot x 2 mt): depth 32
#pragma unroll
    for (int b = 0; b < 16; ++b) {
        float sa0 = sm0, sa1 = sm1, sb0 = 0.f, sb1 = 0.f;
#pragma unroll
        for (int ot = 0; ot < 8; ot += 2) {
            f32x4 aq0 = *(f32x4*)&As[b * 128 + ot * 16 + q * 4];        // broadcast
            f32x4 aq1 = *(f32x4*)&As[b * 128 + (ot + 1) * 16 + q * 4];
#pragma unroll
            for (int r = 0; r < 4; ++r) {
                sa0 += fabsf(acc[0][ot][r]     + aq0[r]) * w2q[ot][r];
                sa1 += fabsf(acc[1][ot][r]     + aq0[r]) * w2q[ot][r];
                sb0 += fabsf(acc[0][ot + 1][r] + aq1[r]) * w2q[ot + 1][r];
                sb1 += fabsf(acc[1][ot + 1][r] + aq1[r]) * w2q[ot + 1][r];
            }
        }
        float s0 = sa0 + sb0, s1 = sa1 + sb1;
        s0 += __shfl_xor(s0, 16, 64);
        s0 += __shfl_xor(s0, 32, 64);
        s1 += __shfl_xor(s1, 16, 64);
        s1 += __shfl_xor(s1, 32, 64);
        if (q == (b & 3)) {
            pb[b * 136 + r0] = (ushort)f2bs(v0 ? __expf(s0) : 0.f);
            pb[b * 136 + r1] = (ushort)f2bs(v1 ? __expf(s1) : 0.f);
        }
    }
    __syncthreads();

    // ---- pool via MFMA: D = P[16b x 128m] . in[128m x 128d]; wave owns 32 d ----
    f32x4 pd[2];
    pd[0] = (f32x4){0.f, 0.f, 0.f, 0.f};
    pd[1] = (f32x4){0.f, 0.f, 0.f, 0.f};
#pragma unroll
    for (int ks = 0; ks < 4; ++ks) {
        bf16x8 pf = *(const bf16x8*)&pb[c * 136 + ks * 32 + q * 8];  // A-frag P[b=c][k]
#pragma unroll
        for (int t = 0; t < 2; ++t) {
            const int dloc = w * 32 + t * 16 + c;
            bf16x8 bf;
#pragma unroll
            for (int j = 0; j < 8; ++j)
                bf[j] = (short)ins[(ks * 32 + q * 8 + j) * 136 + dloc];
            pd[t] = __builtin_amdgcn_mfma_f32_16x16x32_bf16(pf, bf, pd[t], 0, 0, 0);
        }
    }
    // pd[t][r] = pool[b = q*4+r][d = w*32 + t*16 + c]
#pragma unroll
    for (int t = 0; t < 2; ++t)
#pragma unroll
        for (int r = 0; r < 4; ++r)
            pacc[((size_t)bid * 16 + q * 4 + r) * 128 + w * 32 + t * 16 + c] =
                (ushort)f2bs(pd[t][r]);

    // ---- block lsum from pb: thread (b = tid>>4, jj = tid&15) covers 8 m ----
    {
        const int bb = tid >> 4, jj = tid & 15;
        const ushort* pr = &pb[bb * 136 + jj * 8];
        float part = 0.f;
#pragma unroll
        for (int j2 = 0; j2 < 8; ++j2) part += bs2f(pr[j2]);
#pragma unroll
        for (int off = 1; off < 16; off <<= 1) part += __shfl_xor(part, off, 64);
        if (jj == 0) lsum_g[bid * 16 + bb] = part;
    }
}

__global__ __launch_bounds__(256) void kC1(
    const float* __restrict__ lsum_g, const ushort* __restrict__ pacc,
    float* __restrict__ acc2, float* __restrict__ lsum2,
    int* __restrict__ counter, float* __restrict__ out, int nb) {
    const int b = blockIdx.x >> 4, s = blockIdx.x & 15;
    const int t = threadIdx.x;
    __shared__ float reda[2 * 128];
    __shared__ float redl[2];
    const int cs = (nb + 15) >> 4;
    const int blk0 = s * cs;
    int blk1 = blk0 + cs; if (blk1 > nb) blk1 = nb;
    const int dd = t & 127, h = t >> 7;
    float ac = 0.f, ls = 0.f;
    for (int blk = blk0 + h; blk < blk1; blk += 2) {
        ac += bs2f(pacc[((size_t)blk * 16 + b) * 128 + dd]);
        ls += lsum_g[blk * 16 + b];
    }
    reda[h * 128 + dd] = ac;
    if (dd == 0) redl[h] = ls;
    __syncthreads();
    if (h == 0) {
        atomicAdd(&acc2[b * 128 + dd], reda[dd] + reda[128 + dd]);
        if (dd == 0) atomicAdd(&lsum2[b], redl[0] + redl[1]);
    }

    // ---- finisher: last of 256 blocks divides and writes out ----
    __threadfence();
    __shared__ int isLast;
    if (t == 0) isLast = (atomicAdd(counter, 1) == 255);
    __syncthreads();
    if (isLast) {
        for (int i = t; i < 2048; i += 256) {
            float a = atomicAdd(&acc2[i], 0.f);        // coherent read
            float l = atomicAdd(&lsum2[i >> 7], 0.f);  // coherent read
            out[i] = a / l;
        }
    }
}

extern "C" void kernel_launch(void* const* d_in, const int* in_sizes, int n_in,
                              void* d_out, int out_size, void* d_ws, size_t ws_size,
                              hipStream_t stream) {
    const float* xx = (const float*)d_in[0];
    const float* in = (const float*)d_in[1];
    // d_in[2] = adj, unused
    const float* W1 = (const float*)d_in[3];
    const float* W2 = (const float*)d_in[4];
    float* out = (float*)d_out;

    const int M = in_sizes[1] / 128;
    const int nb = (M + 127) / 128;

    float* ws = (float*)d_ws;
    float* A       = ws;                            // 2048
    float* acc2    = A + 2048;                      // 2048
    float* lsum2   = acc2 + 2048;                   // 16
    int*   counter = (int*)(lsum2 + 16);            // 1 (+15 pad)
    float* lsum_g  = (float*)(counter + 16);        // nb*16
    ushort* w1b    = (ushort*)(lsum_g + (size_t)nb * 16);  // 16384
    ushort* pacc   = w1b + 16384;                   // nb*16*128 bf16 (~3.2 MB)

    kA  <<<73, 256, 0, stream>>>(W1, xx, w1b, A, acc2, lsum2, counter);
    kB  <<<nb, 256, 0, stream>>>(in, w1b, W2, A, lsum_g, pacc, M);
    kC1 <<<256, 256, 0, stream>>>(lsum_g, pacc, acc2, lsum2, counter, out, nb);
}

// Round 12
// 136.594 us; speedup vs baseline: 1.3289x; 1.3289x over previous
//
#include <hip/hip_runtime.h>
#include <hip/hip_bf16.h>
#include <math.h>

// B=16, D=128, OUT=128, M runtime (100000).
// v13 = consolidation: v12's kB (clamped named prefetch, no spill, ~50us)
//   + v9's proven plain-store tail kC1+kFin (8+3us).
// v12 lesson (closes the v5/v6 file): device-scope __threadfence() executed
//   per-block costs ~50us on MI355X (cross-XCD L2 writeback stall) -- kC1
//   8->57us with VALUBusy 0.5%. It was the fence, not atomic contention.
//   NEVER use threadfence/counter/finisher single-kernel patterns here.
// Carried: 128-row tile (v10 falsified 64-row), fused staging
//   (reg->cvt->MFMA + ds_write), relu-split scores (4-chain, per-b const
//   dropped -- softmax shift-inv), plain bf16 pacc stores (atomics
//   abandoned), clamped unconditional prefetch (v11 lesson: conditional
//   zero-fill loads spill).

typedef __attribute__((ext_vector_type(8))) short bf16x8;
typedef __attribute__((ext_vector_type(4))) float f32x4;

__device__ __forceinline__ short f2bs(float f) {
    __hip_bfloat16 h = __float2bfloat16(f);
    return *reinterpret_cast<short*>(&h);
}
__device__ __forceinline__ float bs2f(ushort u) {
    union { unsigned int i; float f; } v; v.i = ((unsigned)u) << 16; return v.f;
}
__device__ __forceinline__ bf16x8 pack8(float4 a, float4 b) {
    bf16x8 r;
    r[0] = f2bs(a.x); r[1] = f2bs(a.y); r[2] = f2bs(a.z); r[3] = f2bs(a.w);
    r[4] = f2bs(b.x); r[5] = f2bs(b.y); r[6] = f2bs(b.z); r[7] = f2bs(b.w);
    return r;
}

__global__ __launch_bounds__(256) void kA(const float* __restrict__ W1,
                                          const float* __restrict__ xx,
                                          ushort* __restrict__ w1b,
                                          float* __restrict__ A) {
    const int bi = blockIdx.x, t = threadIdx.x;
    if (bi < 64) {
        int idx = bi * 256 + t;              // 16384 = 128o * 128d
        int o = idx >> 7, d = idx & 127;
        w1b[idx] = (ushort)f2bs(W1[o * 256 + 128 + d]);
        return;
    }
    __shared__ float xxs[16 * 132];
    __shared__ float w1s[16 * 132];
    const int og0 = (bi - 64) * 16;
#pragma unroll
    for (int i = 0; i < 2; ++i) {
        int idx = t + 256 * i;               // 512 float4 = 16 rows * 32
        int r = idx >> 5, c4 = (idx & 31) << 2;
        *(float4*)&xxs[r * 132 + c4] = *(const float4*)&xx[r * 128 + c4];
        *(float4*)&w1s[r * 132 + c4] = *(const float4*)&W1[(og0 + r) * 256 + c4];
    }
    __syncthreads();
    const int ol = t >> 4, b = t & 15;
    float acc = 0.f;
#pragma unroll
    for (int d4 = 0; d4 < 32; ++d4) {
        float4 xv = *(float4*)&xxs[b * 132 + d4 * 4];
        float4 wv = *(float4*)&w1s[ol * 132 + d4 * 4];
        acc += xv.x * wv.x + xv.y * wv.y + xv.z * wv.z + xv.w * wv.w;
    }
    A[b * 128 + og0 + ol] = acc;
}

__global__ __launch_bounds__(256, 3) void kB(
    const float* __restrict__ in, const ushort* __restrict__ w1b,
    const float* __restrict__ W2, const float* __restrict__ A,
    float* __restrict__ lsum_g, ushort* __restrict__ pacc, int M) {
    __shared__ ushort ins[128 * 136];  // bf16 in-tile [m][d]
    __shared__ float As[16 * 128];     // A[b][o]
    __shared__ ushort pb[16 * 136];    // p bf16 [b][m(128)+pad]

    const int tid = threadIdx.x, bid = blockIdx.x;
    const int m0 = bid * 128;
    const int w = tid >> 6, lane = tid & 63;
    const int c = lane & 15, q = lane >> 4;
    const int lim = (M - m0 < 128) ? (M - m0) : 128;

    // ---- rows (clamped: no conditionals -> clean liveness, no spill) ----
    const int r0 = w * 32 + c;            // local row, mt=0
    const int r1 = r0 + 16;               // local row, mt=1
    const bool v0 = r0 < lim, v1 = r1 < lim;
    int cr0 = m0 + r0; if (cr0 > M - 1) cr0 = M - 1;
    int cr1 = m0 + r1; if (cr1 > M - 1) cr1 = M - 1;
    const float* __restrict__ row0 = in + (size_t)cr0 * 128;
    const float* __restrict__ row1 = in + (size_t)cr1 * 128;

    // ---- PREFETCH: 16 named float4, unconditional, issued before any LDS ----
    const int kq = q * 8;
    float4 pA0 = *(const float4*)&row0[kq];       float4 pA1 = *(const float4*)&row0[kq + 4];
    float4 pB0 = *(const float4*)&row0[kq + 32];  float4 pB1 = *(const float4*)&row0[kq + 36];
    float4 pC0 = *(const float4*)&row0[kq + 64];  float4 pC1 = *(const float4*)&row0[kq + 68];
    float4 pD0 = *(const float4*)&row0[kq + 96];  float4 pD1 = *(const float4*)&row0[kq + 100];
    float4 qA0 = *(const float4*)&row1[kq];       float4 qA1 = *(const float4*)&row1[kq + 4];
    float4 qB0 = *(const float4*)&row1[kq + 32];  float4 qB1 = *(const float4*)&row1[kq + 36];
    float4 qC0 = *(const float4*)&row1[kq + 64];  float4 qC1 = *(const float4*)&row1[kq + 68];
    float4 qD0 = *(const float4*)&row1[kq + 96];  float4 qD1 = *(const float4*)&row1[kq + 100];

    // ---- As stage (2048 floats, 2 float4/thread) overlaps load flight ----
#pragma unroll
    for (int i = 0; i < 2; ++i) {
        int idx = tid + 256 * i;
        *(float4*)&As[idx * 4] = *(const float4*)&A[idx * 4];
    }

    // ---- np^T via MFMA: pack prefetched rows -> {MFMA operand + ds_write} ----
    f32x4 acc[2][8];
#pragma unroll
    for (int mt = 0; mt < 2; ++mt)
#pragma unroll
        for (int ot = 0; ot < 8; ++ot) acc[mt][ot] = (f32x4){0.f, 0.f, 0.f, 0.f};

#define NP_STEP(kb, Pa, Pb, Qa, Qb)                                               \
    {                                                                             \
        const int k0 = (kb) * 32 + kq;                                            \
        bf16x8 bv0 = pack8(Pa, Pb);                                               \
        bf16x8 bv1 = pack8(Qa, Qb);                                               \
        *(bf16x8*)&ins[r0 * 136 + k0] = bv0;                                      \
        *(bf16x8*)&ins[r1 * 136 + k0] = bv1;                                      \
        _Pragma("unroll")                                                         \
        for (int ot = 0; ot < 8; ++ot) {                                          \
            bf16x8 av = *(const bf16x8*)(w1b + (ot * 16 + c) * 128 + k0);         \
            acc[0][ot] = __builtin_amdgcn_mfma_f32_16x16x32_bf16(av, bv0, acc[0][ot], 0, 0, 0); \
            acc[1][ot] = __builtin_amdgcn_mfma_f32_16x16x32_bf16(av, bv1, acc[1][ot], 0, 0, 0); \
        }                                                                         \
    }
    NP_STEP(0, pA0, pA1, qA0, qA1)
    NP_STEP(1, pB0, pB1, qB0, qB1)
    NP_STEP(2, pC0, pC1, qC0, qC1)
    NP_STEP(3, pD0, pD1, qD0, qD1)
#undef NP_STEP
    // acc[mt][ot][r] = np[m = w*32 + mt*16 + c][o = ot*16 + q*4 + r]

    // ---- per-lane w2 quads, pre-scaled by 0.5 (hoisted above barrier) ----
    f32x4 w2q[8];
#pragma unroll
    for (int ot = 0; ot < 8; ++ot) {
        f32x4 wv = *(const f32x4*)&W2[ot * 16 + q * 4];
        w2q[ot] = wv * 0.5f;
    }
    __syncthreads();   // ins + As complete

    // ---- sm = 0.5*Sum_o np*w2 per m-tile (b-invariant, hoisted) ----
    float sm0 = 0.f, sm1 = 0.f;
#pragma unroll
    for (int ot = 0; ot < 8; ++ot)
#pragma unroll
        for (int r = 0; r < 4; ++r) {
            sm0 += acc[0][ot][r] * w2q[ot][r];
            sm1 += acc[1][ot][r] * w2q[ot][r];
        }

    // ---- scores: s(b,m) = sm + 0.5*Sum_o |np+A|*w2 (per-b const dropped) ----
    // 4 independent chains (even/odd ot x 2 mt): depth 32
#pragma unroll
    for (int b = 0; b < 16; ++b) {
        float sa0 = sm0, sa1 = sm1, sb0 = 0.f, sb1 = 0.f;
#pragma unroll
        for (int ot = 0; ot < 8; ot += 2) {
            f32x4 aq0 = *(f32x4*)&As[b * 128 + ot * 16 + q * 4];        // broadcast
            f32x4 aq1 = *(f32x4*)&As[b * 128 + (ot + 1) * 16 + q * 4];
#pragma unroll
            for (int r = 0; r < 4; ++r) {
                sa0 += fabsf(acc[0][ot][r]     + aq0[r]) * w2q[ot][r];
                sa1 += fabsf(acc[1][ot][r]     + aq0[r]) * w2q[ot][r];
                sb0 += fabsf(acc[0][ot + 1][r] + aq1[r]) * w2q[ot + 1][r];
                sb1 += fabsf(acc[1][ot + 1][r] + aq1[r]) * w2q[ot + 1][r];
            }
        }
        float s0 = sa0 + sb0, s1 = sa1 + sb1;
        s0 += __shfl_xor(s0, 16, 64);
        s0 += __shfl_xor(s0, 32, 64);
        s1 += __shfl_xor(s1, 16, 64);
        s1 += __shfl_xor(s1, 32, 64);
        if (q == (b & 3)) {
            pb[b * 136 + r0] = (ushort)f2bs(v0 ? __expf(s0) : 0.f);
            pb[b * 136 + r1] = (ushort)f2bs(v1 ? __expf(s1) : 0.f);
        }
    }
    __syncthreads();

    // ---- pool via MFMA: D = P[16b x 128m] . in[128m x 128d]; wave owns 32 d ----
    f32x4 pd[2];
    pd[0] = (f32x4){0.f, 0.f, 0.f, 0.f};
    pd[1] = (f32x4){0.f, 0.f, 0.f, 0.f};
#pragma unroll
    for (int ks = 0; ks < 4; ++ks) {
        bf16x8 pf = *(const bf16x8*)&pb[c * 136 + ks * 32 + q * 8];  // A-frag P[b=c][k]
#pragma unroll
        for (int t = 0; t < 2; ++t) {
            const int dloc = w * 32 + t * 16 + c;
            bf16x8 bf;
#pragma unroll
            for (int j = 0; j < 8; ++j)
                bf[j] = (short)ins[(ks * 32 + q * 8 + j) * 136 + dloc];
            pd[t] = __builtin_amdgcn_mfma_f32_16x16x32_bf16(pf, bf, pd[t], 0, 0, 0);
        }
    }
    // pd[t][r] = pool[b = q*4+r][d = w*32 + t*16 + c]
#pragma unroll
    for (int t = 0; t < 2; ++t)
#pragma unroll
        for (int r = 0; r < 4; ++r)
            pacc[((size_t)bid * 16 + q * 4 + r) * 128 + w * 32 + t * 16 + c] =
                (ushort)f2bs(pd[t][r]);

    // ---- block lsum from pb: thread (b = tid>>4, jj = tid&15) covers 8 m ----
    {
        const int bb = tid >> 4, jj = tid & 15;
        const ushort* pr = &pb[bb * 136 + jj * 8];
        float part = 0.f;
#pragma unroll
        for (int j2 = 0; j2 < 8; ++j2) part += bs2f(pr[j2]);
#pragma unroll
        for (int off = 1; off < 16; off <<= 1) part += __shfl_xor(part, off, 64);
        if (jj == 0) lsum_g[bid * 16 + bb] = part;
    }
}

__global__ __launch_bounds__(256) void kC1(
    const float* __restrict__ lsum_g, const ushort* __restrict__ pacc,
    float* __restrict__ pacc2, float* __restrict__ lsum2, int nb) {
    const int b = blockIdx.x >> 4, s = blockIdx.x & 15;
    const int t = threadIdx.x;
    __shared__ float reda[2 * 128];
    __shared__ float redl[2];
    const int cs = (nb + 15) >> 4;
    const int blk0 = s * cs;
    int blk1 = blk0 + cs; if (blk1 > nb) blk1 = nb;
    const int dd = t & 127, h = t >> 7;
    float ac = 0.f, ls = 0.f;
    for (int blk = blk0 + h; blk < blk1; blk += 2) {
        ac += bs2f(pacc[((size_t)blk * 16 + b) * 128 + dd]);
        ls += lsum_g[blk * 16 + b];
    }
    reda[h * 128 + dd] = ac;
    if (dd == 0) redl[h] = ls;
    __syncthreads();
    if (h == 0) {
        pacc2[((size_t)s * 16 + b) * 128 + dd] = reda[dd] + reda[128 + dd];
        if (dd == 0) lsum2[s * 16 + b] = redl[0] + redl[1];
    }
}

__global__ void kFin(const float* __restrict__ pacc2, const float* __restrict__ lsum2,
                     float* __restrict__ out) {
    const int b = blockIdx.x, t = threadIdx.x;   // 16 blocks x 128 threads
    float ac = 0.f, ls = 0.f;
#pragma unroll
    for (int s = 0; s < 16; ++s) {
        ac += pacc2[((size_t)s * 16 + b) * 128 + t];
        ls += lsum2[s * 16 + b];
    }
    out[b * 128 + t] = ac / ls;
}

extern "C" void kernel_launch(void* const* d_in, const int* in_sizes, int n_in,
                              void* d_out, int out_size, void* d_ws, size_t ws_size,
                              hipStream_t stream) {
    const float* xx = (const float*)d_in[0];
    const float* in = (const float*)d_in[1];
    // d_in[2] = adj, unused
    const float* W1 = (const float*)d_in[3];
    const float* W2 = (const float*)d_in[4];
    float* out = (float*)d_out;

    const int M = in_sizes[1] / 128;
    const int nb = (M + 127) / 128;

    float* ws = (float*)d_ws;
    float* A      = ws;                             // 2048
    float* lsum_g = A + 2048;                       // nb*16
    float* pacc2  = lsum_g + (size_t)nb * 16;       // 256*128
    float* lsum2  = pacc2 + 256 * 128;              // 256
    ushort* w1b   = (ushort*)(lsum2 + 256);         // 16384
    ushort* pacc  = w1b + 16384;                    // nb*16*128 bf16 (~3.2 MB)

    kA  <<<72, 256, 0, stream>>>(W1, xx, w1b, A);
    kB  <<<nb, 256, 0, stream>>>(in, w1b, W2, A, lsum_g, pacc, M);
    kC1 <<<256, 256, 0, stream>>>(lsum_g, pacc, pacc2, lsum2, nb);
    kFin<<<16, 128, 0, stream>>>(pacc2, lsum2, out);
}